// Round 11
// baseline (124.671 us; speedup 1.0000x reference)
//
#include <hip/hip_runtime.h>
#include <hip/hip_bf16.h>
#include <stdint.h>

// ---------------- common types / helpers ----------------
typedef __attribute__((ext_vector_type(8))) short short8v;   // 8 x bf16 (4 VGPRs)
typedef __attribute__((ext_vector_type(4))) float floatx4;
typedef __attribute__((ext_vector_type(4))) unsigned uintx4;

#define DEV __device__ __forceinline__

DEV ushort f2bf(float f) {                      // RNE float -> bf16 bits
  union { float f; unsigned u; } v; v.f = f;
  unsigned r = v.u + 0x7fffu + ((v.u >> 16) & 1u);
  return (ushort)(r >> 16);
}
DEV float bf2f(ushort b) {
  union { unsigned u; float f; } v; v.u = ((unsigned)b) << 16;
  return v.f;
}
DEV unsigned cvtpk(float lo, float hi) {        // packed f32->bf16 (RNE), 1 inst
  unsigned r;
  asm("v_cvt_pk_bf16_f32 %0, %1, %2" : "=v"(r) : "v"(lo), "v"(hi));
  return r;
}
// XOR swizzle for 64-col bf16 tiles (128B rows)
DEV int swz(int row, int colByte) {
  return row * 128 + (colByte ^ ((row & 7) << 4));
}
// XOR swizzle for 128-col bf16 tiles (256B rows)
DEV int swz256(int row, int colByte) {
  return row * 256 + (colByte ^ ((row & 7) << 4));
}
DEV floatx4 mfma16(short8v a, short8v b, floatx4 c) {
  return __builtin_amdgcn_mfma_f32_16x16x32_bf16(a, b, c, 0, 0, 0);
}

#define GLD_LDS16(g, l)                                                   \
  __builtin_amdgcn_global_load_lds(                                       \
      (const __attribute__((address_space(1))) void*)(g),                 \
      (__attribute__((address_space(3))) void*)(l), 16, 0, 0)

// problem constants
constexpr int Bc = 8, HEADS = 8, NTOK = 4096, CDIM = 512, DH = 64;
constexpr float SCALE = 0.125f;   // DH^-0.5
constexpr int NCH = 8, CHK = 512;    // key chunks for qkexp (4 sub-tiles of 128)

// proj_w fp32 -> bf16 (pw only; to_out_w converted inline in k_midm2)
__global__ __launch_bounds__(256) void k_f2bfw1(const float* __restrict__ a,
                                                ushort* __restrict__ da) {
  int j = blockIdx.x * 256 + threadIdx.x;    // 0 .. 65535
  float4 f = ((const float4*)a)[j];
  ushort4 o;
  o.x = f2bf(f.x); o.y = f2bf(f.y); o.z = f2bf(f.z); o.w = f2bf(f.w);
  ((ushort4*)da)[j] = o;
}

// B-panel staging into LDS: 128 rows x 512 k bf16 (128 KB), chunk-XOR swizzled
// within each 128B group of 8 16B-chunks so frag reads are ~2-way conflict only.
// src rows are CDIM(=512)-ushort rows of `Bsrc + n0`.
DEV void stageB(const ushort* __restrict__ Bsrc, int n0, char* sB, int t) {
#pragma unroll
  for (int i = 0; i < 16; ++i) {
    int flat = i * 512 + t;              // 0..8191 16B-chunks
    int n = flat >> 6, c = flat & 63;
    int sc = (c & ~7) | ((c & 7) ^ (n & 7));
    GLD_LDS16(Bsrc + (size_t)(n0 + n) * CDIM + sc * 8, sB + flat * 16);
  }
}
// read B frag: n-row n, global 16B-chunk gc (= k_bf16*2/16)
DEV short8v readB(const char* sB, int n, int gc) {
  int c = (gc & ~7) | ((gc & 7) ^ (n & 7));
  return *(const short8v*)(sB + n * 1024 + c * 16);
}

// ================= gemm1: w[32768,512] = bf16(x) @ pw^T =================
// B-resident LDS (128-col panel, full K), A streamed global->reg with inline
// fp32->bf16 cvt, ZERO barriers in the hot loop. grid 256 = 64 strips x 4
// panels; XCD-chunked so the 4 panel-siblings of a strip share one L2.
__global__ __launch_bounds__(512, 1) void k_gemm1(const float* __restrict__ A,
                                                  const ushort* __restrict__ Bm,
                                                  ushort* __restrict__ Cout) {
  __shared__ char sB[131072] __attribute__((aligned(128)));
  const int t = threadIdx.x, w = t >> 6, l = t & 63;
  const int lg = l >> 4, li = l & 15;
  const int bid = blockIdx.x;               // 256
  const int xcd = bid & 7, loc = bid >> 3;  // loc 0..31
  const int strip = xcd * 8 + (loc >> 2);   // 0..63 -> 512 rows each
  const int n0 = (loc & 3) * 128;           // panel

  stageB(Bm, n0, sB, t);
  __syncthreads();

#pragma unroll
  for (int pass = 0; pass < 2; ++pass) {
    const size_t r0 = (size_t)strip * 512 + pass * 256 + w * 32;
    floatx4 acc[2][8] = {};
    const float* ga0 = A + (r0 + li) * CDIM + lg * 8;
    const float* ga1 = A + (r0 + 16 + li) * CDIM + lg * 8;
    float4 c00 = *(const float4*)ga0, c01 = *(const float4*)(ga0 + 4);
    float4 c10 = *(const float4*)ga1, c11 = *(const float4*)(ga1 + 4);
#pragma unroll
    for (int kt = 0; kt < 16; ++kt) {
      float4 n00, n01, n10, n11;
      if (kt < 15) {                       // 1-deep prefetch; no barrier anywhere
        const float* g0 = ga0 + (kt + 1) * 32;
        const float* g1 = ga1 + (kt + 1) * 32;
        n00 = *(const float4*)g0; n01 = *(const float4*)(g0 + 4);
        n10 = *(const float4*)g1; n11 = *(const float4*)(g1 + 4);
      }
      uintx4 u0, u1;
      u0.x = cvtpk(c00.x, c00.y); u0.y = cvtpk(c00.z, c00.w);
      u0.z = cvtpk(c01.x, c01.y); u0.w = cvtpk(c01.z, c01.w);
      u1.x = cvtpk(c10.x, c10.y); u1.y = cvtpk(c10.z, c10.w);
      u1.z = cvtpk(c11.x, c11.y); u1.w = cvtpk(c11.z, c11.w);
      short8v a0 = *(short8v*)&u0, a1 = *(short8v*)&u1;
#pragma unroll
      for (int nf = 0; nf < 8; ++nf) {
        short8v bf = readB(sB, nf * 16 + li, kt * 4 + lg);
        acc[0][nf] = mfma16(a0, bf, acc[0][nf]);
        acc[1][nf] = mfma16(a1, bf, acc[1][nf]);
      }
      c00 = n00; c01 = n01; c10 = n10; c11 = n11;
    }
#pragma unroll
    for (int mi = 0; mi < 2; ++mi)
#pragma unroll
      for (int nf = 0; nf < 8; ++nf)
#pragma unroll
        for (int r = 0; r < 4; ++r) {
          size_t row = r0 + mi * 16 + lg * 4 + r;
          Cout[row * CDIM + n0 + nf * 16 + li] = f2bf(acc[mi][nf][r]);
        }
  }
}

// ================= gemm3: out[b,n,d] = sum_hq attnT[b,h,n,q]*M2T[b,d,hq] + bias =================
// same B-resident barrier-free structure; A = attnT bf16; b == XCD.
__global__ __launch_bounds__(512, 1) void k_gemm3(const ushort* __restrict__ attnT, // [b,8,4096,64]
                                                  const ushort* __restrict__ M2T,   // [b,512,512]
                                                  float* __restrict__ out,          // [b,4096,512]
                                                  const float* __restrict__ bias) {
  __shared__ char sB[131072] __attribute__((aligned(128)));
  const int t = threadIdx.x, w = t >> 6, l = t & 63;
  const int lg = l >> 4, li = l & 15;
  const int bid = blockIdx.x;               // 256
  const int b = bid & 7, loc = bid >> 3;    // one batch per XCD
  const int strip = loc >> 2;               // 0..7 -> 512 token rows
  const int n0 = (loc & 3) * 128;           // out-channel panel

  stageB(M2T + (size_t)b * 262144, n0, sB, t);
  __syncthreads();

#pragma unroll
  for (int pass = 0; pass < 2; ++pass) {
    const int r0 = strip * 512 + pass * 256 + w * 32;
    floatx4 acc[2][8] = {};
    // A frag: h = kt>>1, q_byte = (kt&1)*64 + lg*16; rows r0+mi*16+li (128B rows)
    const char* gaBase = (const char*)(attnT + (size_t)b * 8 * NTOK * 64);
    short8v cA0, cA1;
    {
      const char* g = gaBase + (size_t)(r0 + li) * 128 + lg * 16;
      cA0 = *(const short8v*)g;
      cA1 = *(const short8v*)(g + 16 * 128);
    }
#pragma unroll
    for (int kt = 0; kt < 16; ++kt) {
      short8v nA0, nA1;
      if (kt < 15) {
        int k1 = kt + 1;
        const char* g = gaBase + ((size_t)(k1 >> 1) * NTOK + r0 + li) * 128 +
                        (k1 & 1) * 64 + lg * 16;
        nA0 = *(const short8v*)g;
        nA1 = *(const short8v*)(g + 16 * 128);
      }
#pragma unroll
      for (int nf = 0; nf < 8; ++nf) {
        short8v bf = readB(sB, nf * 16 + li, kt * 4 + lg);
        acc[0][nf] = mfma16(cA0, bf, acc[0][nf]);
        acc[1][nf] = mfma16(cA1, bf, acc[1][nf]);
      }
      cA0 = nA0; cA1 = nA1;
    }
#pragma unroll
    for (int mi = 0; mi < 2; ++mi)
#pragma unroll
      for (int nf = 0; nf < 8; ++nf) {
        int col = n0 + nf * 16 + li;
        float bv = bias[col];
#pragma unroll
        for (int r = 0; r < 4; ++r) {
          int row = r0 + mi * 16 + lg * 4 + r;
          out[((size_t)b * NTOK + row) * CDIM + col] = acc[mi][nf][r] + bv;
        }
      }
  }
}

// ---------------- adaptive 8x8 pool + pre-swizzled bf16 Q tiles ----------------
__global__ __launch_bounds__(256) void k_pool(const ushort* __restrict__ wm,
                                              float* __restrict__ rep,
                                              ushort* __restrict__ qbf) {
  const int blk = blockIdx.x;      // b*64 + qi
  const int b = blk >> 6, qi = blk & 63;
  const int ph = qi >> 3, pw = qi & 7;
  const int c0 = threadIdx.x * 2;
  float a0 = 0.f, a1 = 0.f;
  for (int u = 0; u < 64; ++u) {
    int n = (ph * 8 + (u >> 3)) * 64 + pw * 8 + (u & 7);
    unsigned v = *(const unsigned*)(wm + ((size_t)b * NTOK + n) * CDIM + c0);
    a0 += bf2f((ushort)(v & 0xffff));
    a1 += bf2f((ushort)(v >> 16));
  }
  a0 *= 0.015625f; a1 *= 0.015625f;
  float* dst = rep + ((size_t)b * 64 + qi) * CDIM + c0;
  dst[0] = a0;
  dst[1] = a1;
  // bf16 Q tile, swizzled layout per (b,h): [64 q][64 d]
  int h = c0 >> 6, d0 = c0 & 63;   // d0 even
  unsigned pack = (unsigned)f2bf(a0) | ((unsigned)f2bf(a1) << 16);
  *(unsigned*)((char*)qbf + ((size_t)(b * 8 + h)) * 8192 + swz(qi, d0 * 2)) = pack;
}

// ---------------- qkexp: per (bh, chunk of 512 keys; 4 sub-tiles of 128) ----------------
__global__ __launch_bounds__(256) void k_qkexp(const ushort* __restrict__ wmat,
                                               const ushort* __restrict__ qbf,
                                               ushort* __restrict__ attnT,  // [bh,4096,64]
                                               float* __restrict__ pvP,     // [bh,8,64,64]
                                               float* __restrict__ rsumP) { // [bh,8,64]
  __shared__ char smem[57344] __attribute__((aligned(128)));
  ushort* sQ  = (ushort*)smem;            // [64 q][64 d]   8KB swizzled
  ushort* sK  = (ushort*)(smem + 8192);   // [128 n][64 d] 16KB swizzled
  ushort* sVT = (ushort*)(smem + 24576);  // [64 d][128 n] 16KB swizzled (256B rows)
  ushort* sP  = (ushort*)(smem + 40960);  // [64 q][128 k] 16KB swizzled (256B rows)

  const int bh = blockIdx.y, ch = blockIdx.x;
  const int b = bh >> 3, h = bh & 7;
  const int t = threadIdx.x, w = t >> 6, l = t & 63;
  const int lg = l >> 4, li = l & 15;

  // stage Q (pre-swizzled in qbf -> linear copy)
  {
    const char* qsrc = (const char*)(qbf + (size_t)bh * 4096);
#pragma unroll
    for (int i = 0; i < 2; ++i) {
      int flat = i * 256 + t;
      GLD_LDS16(qsrc + flat * 16, (char*)sQ + flat * 16);
    }
  }

  float rs[4] = {};
  floatx4 pv[4] = {};
  short8v qa[2];
  bool qaLoaded = false;

  for (int sc = 0; sc < 4; ++sc) {
    const ushort* wbase = wmat + ((size_t)b * NTOK + ch * CHK + sc * 128) * CDIM + h * DH;
    __syncthreads();
    // stage K tile (source pre-swizzled)
#pragma unroll
    for (int i = 0; i < 4; ++i) {
      int flat = i * 256 + t;
      int row = flat >> 3, pch = flat & 7;
      int sch = pch ^ (row & 7);
      GLD_LDS16(wbase + (size_t)row * CDIM + sch * 8, (char*)sK + flat * 16);
    }
    // stage V transposed: [d][n] — packed u32 writes (n-pair per thread)
    {
      int u = t & 63;                 // n-pair: columns 2u, 2u+1
      int dh2 = (t >> 6) * 16;        // 16 d's
      const ushort* g0 = wbase + (size_t)(2 * u) * CDIM + dh2;
      const ushort* g1 = g0 + CDIM;
      short8v a0 = *(const short8v*)g0;
      short8v a1 = *(const short8v*)(g0 + 8);
      short8v b0 = *(const short8v*)g1;
      short8v b1 = *(const short8v*)(g1 + 8);
#pragma unroll
      for (int j = 0; j < 8; ++j) {
        unsigned w0 = ((unsigned)(ushort)a0[j]) | (((unsigned)(ushort)b0[j]) << 16);
        *(unsigned*)((char*)sVT + swz256(dh2 + j, 4 * u)) = w0;
        unsigned w1 = ((unsigned)(ushort)a1[j]) | (((unsigned)(ushort)b1[j]) << 16);
        *(unsigned*)((char*)sVT + swz256(dh2 + 8 + j, 4 * u)) = w1;
      }
    }
    __syncthreads();

    if (!qaLoaded) {
      qaLoaded = true;
#pragma unroll
      for (int kk = 0; kk < 2; ++kk)
        qa[kk] = *(const short8v*)((const char*)sQ + swz(w * 16 + li, (kk * 32 + lg * 8) * 2));
    }

    // QK^T
    floatx4 s[8] = {};
#pragma unroll
    for (int kk = 0; kk < 2; ++kk) {
      int cb = (kk * 32 + lg * 8) * 2;
#pragma unroll
      for (int kf = 0; kf < 8; ++kf) {
        short8v kb = *(const short8v*)((const char*)sK + swz(kf * 16 + li, cb));
        s[kf] = mfma16(qa[kk], kb, s[kf]);
      }
    }

    // exp, rowsum partial, attnT store, sP write
#pragma unroll
    for (int kf = 0; kf < 8; ++kf) {
      ushort pb[4];
#pragma unroll
      for (int r = 0; r < 4; ++r) {
        float p = __expf(s[kf][r] * SCALE);
        rs[r] += p;
        pb[r] = f2bf(p);
        int q = w * 16 + lg * 4 + r;
        *(ushort*)((char*)sP + swz256(q, (kf * 16 + li) * 2)) = pb[r];
      }
      int key = ch * CHK + sc * 128 + kf * 16 + li;
      ushort4 pk; pk.x = pb[0]; pk.y = pb[1]; pk.z = pb[2]; pk.w = pb[3];
      *(ushort4*)(attnT + ((size_t)bh * NTOK + key) * 64 + w * 16 + lg * 4) = pk;
    }

    // PV partial accumulate over these 128 keys
#pragma unroll
    for (int kk4 = 0; kk4 < 4; ++kk4) {
      int cb = kk4 * 64 + lg * 16;
      short8v pa = *(const short8v*)((const char*)sP + swz256(w * 16 + li, cb));
#pragma unroll
      for (int nf = 0; nf < 4; ++nf) {
        short8v vb = *(const short8v*)((const char*)sVT + swz256(nf * 16 + li, cb));
        pv[nf] = mfma16(pa, vb, pv[nf]);
      }
    }
  }

#pragma unroll
  for (int r = 0; r < 4; ++r) {
    float v = rs[r];
    for (int mask = 1; mask < 16; mask <<= 1) v += __shfl_xor(v, mask);
    if (li == 0) rsumP[((size_t)bh * NCH + ch) * 64 + w * 16 + lg * 4 + r] = v;
  }
  float* pvdst = pvP + ((size_t)bh * NCH + ch) * 4096;
#pragma unroll
  for (int nf = 0; nf < 4; ++nf)
#pragma unroll
    for (int r = 0; r < 4; ++r)
      pvdst[(w * 16 + lg * 4 + r) * 64 + nf * 16 + li] = pv[nf][r];
}

// ---------------- midm2: chunk-reduce + reph update + self-attn + xd + M2T ----------------
// to_out_w read as fp32 and converted inline (saves the tow f2bf pass).
__global__ __launch_bounds__(256) void k_midm2(const float* __restrict__ rep,
                                               const float* __restrict__ pvP,
                                               const float* __restrict__ rsumP,
                                               const float* __restrict__ step_rep,
                                               const float* __restrict__ step_x,
                                               const float* __restrict__ tow,   // fp32 [512,512]
                                               ushort* __restrict__ m2t) {
  __shared__ float sSum[64];
  __shared__ float sRd[4096];
  __shared__ float sR[64 * 65];
  __shared__ float sT[64 * 65];
  __shared__ ushort sXd[4096];   // [64 q][64 dd] swizzled bf16
  const int bh = blockIdx.x;
  const int b = bh >> 3, h = bh & 7;
  const int t = threadIdx.x, w = t >> 6, l = t & 63;
  const int lg = l >> 4, li = l & 15;

  if (t < 64) {
    float v = 0.f;
#pragma unroll
    for (int ch = 0; ch < NCH; ++ch) v += rsumP[((size_t)bh * NCH + ch) * 64 + t];
    sSum[t] = v;
  }
  {
    const float* p = pvP + (size_t)bh * NCH * 4096;
#pragma unroll
    for (int j = 0; j < 16; ++j) {
      int idx = t + 256 * j;
      float sm = 0.f;
#pragma unroll
      for (int ch = 0; ch < NCH; ++ch) sm += p[ch * 4096 + idx];
      sRd[idx] = sm;
    }
  }
  __syncthreads();
  {
    int q = t >> 2, d0 = (t & 3) * 16;
    float srep = step_rep[h];
    float inv = 1.f / sSum[q];
    const float* rp = rep + ((size_t)b * 64 + q) * CDIM + h * DH + d0;
#pragma unroll
    for (int j = 0; j < 16; ++j) sR[q * 65 + d0 + j] = rp[j] + srep * (sRd[q * 64 + d0 + j] * inv);
  }
  __syncthreads();
  {
    int q = t >> 2, jb = (t & 3) * 16;
    float a[16];
#pragma unroll
    for (int j = 0; j < 16; ++j) {
      float accd = 0.f;
      for (int d = 0; d < 64; ++d) accd += sR[q * 65 + d] * sR[(jb + j) * 65 + d];
      a[j] = accd * SCALE;
    }
    float mx = a[0];
#pragma unroll
    for (int j = 1; j < 16; ++j) mx = fmaxf(mx, a[j]);
    mx = fmaxf(mx, __shfl_xor(mx, 1));
    mx = fmaxf(mx, __shfl_xor(mx, 2));
    float sm = 0.f;
#pragma unroll
    for (int j = 0; j < 16; ++j) { a[j] = __expf(a[j] - mx); sm += a[j]; }
    sm += __shfl_xor(sm, 1);
    sm += __shfl_xor(sm, 2);
    float inv = 1.f / sm;
#pragma unroll
    for (int j = 0; j < 16; ++j) sT[q * 65 + jb + j] = a[j] * inv;
  }
  __syncthreads();
  {
    int q = t >> 2, db = (t & 3) * 16;
    float accd[16] = {};
    for (int j = 0; j < 64; ++j) {
      float w2 = sT[q * 65 + j];
#pragma unroll
      for (int d = 0; d < 16; ++d) accd[d] += w2 * sR[j * 65 + db + d];
    }
    float sc = step_x[h] / sSum[q];
    ushort o[16] __attribute__((aligned(16)));
#pragma unroll
    for (int d = 0; d < 16; ++d) o[d] = f2bf(accd[d] * sc);
    *(short8v*)((char*)sXd + swz(q, db * 2)) = *(short8v*)&o[0];
    *(short8v*)((char*)sXd + swz(q, db * 2 + 16)) = *(short8v*)&o[8];
  }
  __syncthreads();
  // m2: wave w covers d rows [w*128,(w+1)*128); tow fp32 converted inline
  floatx4 acc[8][4] = {};
#pragma unroll
  for (int kk = 0; kk < 2; ++kk) {
    int dd0 = kk * 32 + lg * 8;
    short8v bf[4];
#pragma unroll
    for (int nf = 0; nf < 4; ++nf)
      bf[nf] = *(const short8v*)((const char*)sXd + swz(nf * 16 + li, dd0 * 2));
#pragma unroll
    for (int m = 0; m < 8; ++m) {
      int d = w * 128 + m * 16 + li;
      const float* g = tow + (size_t)d * CDIM + h * DH + dd0;
      float4 lo = *(const float4*)g;
      float4 hi = *(const float4*)(g + 4);
      uintx4 u;
      u.x = cvtpk(lo.x, lo.y); u.y = cvtpk(lo.z, lo.w);
      u.z = cvtpk(hi.x, hi.y); u.w = cvtpk(hi.z, hi.w);
      short8v af = *(short8v*)&u;
#pragma unroll
      for (int nf = 0; nf < 4; ++nf) acc[m][nf] = mfma16(af, bf[nf], acc[m][nf]);
    }
  }
#pragma unroll
  for (int m = 0; m < 8; ++m)
#pragma unroll
    for (int nf = 0; nf < 4; ++nf)
#pragma unroll
      for (int r = 0; r < 4; ++r) {
        int d = w * 128 + m * 16 + lg * 4 + r;
        int hq = h * 64 + nf * 16 + li;
        m2t[((size_t)b * CDIM + d) * CDIM + hq] = f2bf(acc[m][nf][r]);
      }
}

// ---------------- launch ----------------
extern "C" void kernel_launch(void* const* d_in, const int* in_sizes, int n_in,
                              void* d_out, int out_size, void* d_ws, size_t ws_size,
                              hipStream_t stream) {
  const float* x = (const float*)d_in[0];
  const float* proj_w = (const float*)d_in[1];
  const float* step_rep = (const float*)d_in[2];
  const float* step_x = (const float*)d_in[3];
  const float* to_out_w = (const float*)d_in[4];
  const float* to_out_b = (const float*)d_in[5];
  float* out = (float*)d_out;
  char* ws = (char*)d_ws;
  char* ob = (char*)d_out;   // d_out doubles as scratch until gemm3 overwrites it

  // ws layout:
  ushort* bufA = (ushort*)(ws);                  // attnT                  (32 MiB)
  ushort* bufB = (ushort*)(ws + 33554432);       // w bf16 -> M2T overlay  (32 MiB)
  ushort* pw   = (ushort*)(ws + 67108864);       // proj_w bf16 (512 KiB)
  float*  rep  = (float*)(ws + 68157440);        // pooled rep fp32 (1 MiB)
  // d_out scratch (all dead before gemm3 writes out):
  float*  pvP   = (float*)(ob);                  // PV partials (8.4 MiB)
  ushort* qbf   = (ushort*)(ob + 34603008);      // pre-swizzled Q tiles (512 KiB)
  float*  rsumP = (float*)(ob + 35127296);       // rowsum partials (128 KiB)
  ushort* m2t   = bufB;                          // M2T overlays w after qkexp

  k_f2bfw1<<<256, 256, 0, stream>>>(proj_w, pw);

  k_gemm1<<<256, 512, 0, stream>>>(x, pw, bufB);

  k_pool<<<Bc * 64, 256, 0, stream>>>(bufB, rep, qbf);

  k_qkexp<<<dim3(NCH, Bc * HEADS), 256, 0, stream>>>(bufB, qbf, bufA, pvP, rsumP);

  k_midm2<<<Bc * HEADS, 256, 0, stream>>>(rep, pvP, rsumP, step_rep, step_x, to_out_w, m2t);

  k_gemm3<<<256, 512, 0, stream>>>(bufA, m2t, out, to_out_b);
}

// Round 12
// 113.237 us; speedup vs baseline: 1.1010x; 1.1010x over previous
//
#include <hip/hip_runtime.h>
#include <hip/hip_bf16.h>
#include <stdint.h>

// ---------------- common types / helpers ----------------
typedef __attribute__((ext_vector_type(8))) short short8v;   // 8 x bf16 (4 VGPRs)
typedef __attribute__((ext_vector_type(4))) float floatx4;
typedef __attribute__((ext_vector_type(4))) unsigned uintx4;

#define DEV __device__ __forceinline__

DEV ushort f2bf(float f) {                      // RNE float -> bf16 bits
  union { float f; unsigned u; } v; v.f = f;
  unsigned r = v.u + 0x7fffu + ((v.u >> 16) & 1u);
  return (ushort)(r >> 16);
}
DEV float bf2f(ushort b) {
  union { unsigned u; float f; } v; v.u = ((unsigned)b) << 16;
  return v.f;
}
DEV unsigned cvtpk(float lo, float hi) {        // packed f32->bf16 (RNE), 1 inst
  unsigned r;
  asm("v_cvt_pk_bf16_f32 %0, %1, %2" : "=v"(r) : "v"(lo), "v"(hi));
  return r;
}
// XOR swizzle for 64-col bf16 tiles (128B rows)
DEV int swz(int row, int colByte) {
  return row * 128 + (colByte ^ ((row & 7) << 4));
}
// XOR swizzle for 128-col bf16 tiles (256B rows)
DEV int swz256(int row, int colByte) {
  return row * 256 + (colByte ^ ((row & 7) << 4));
}
DEV floatx4 mfma16(short8v a, short8v b, floatx4 c) {
  return __builtin_amdgcn_mfma_f32_16x16x32_bf16(a, b, c, 0, 0, 0);
}

#define GLD_LDS16(g, l)                                                   \
  __builtin_amdgcn_global_load_lds(                                       \
      (const __attribute__((address_space(1))) void*)(g),                 \
      (__attribute__((address_space(3))) void*)(l), 16, 0, 0)

#define WAIT_LGKM0 asm volatile("s_waitcnt lgkmcnt(0)" ::: "memory")
DEV void sbar() {
  __builtin_amdgcn_sched_barrier(0);
  __builtin_amdgcn_s_barrier();
  __builtin_amdgcn_sched_barrier(0);
}

// problem constants
constexpr int Bc = 8, HEADS = 8, NTOK = 4096, CDIM = 512, DH = 64;
constexpr float SCALE = 0.125f;   // DH^-0.5
constexpr int NCH = 16, CHK = 256;   // key chunks for qkexp (2 sub-tiles of 128)

// proj_w fp32 -> bf16 (pw only; to_out_w converted inline in k_midm2)
__global__ __launch_bounds__(256) void k_f2bfw1(const float* __restrict__ a,
                                                ushort* __restrict__ da) {
  int j = blockIdx.x * 256 + threadIdx.x;    // 0 .. 65535
  float4 f = ((const float4*)a)[j];
  ushort4 o;
  o.x = f2bf(f.x); o.y = f2bf(f.y); o.z = f2bf(f.z); o.w = f2bf(f.w);
  ((ushort4*)da)[j] = o;
}

// ================= gemm1: w[M,512] = bf16(x[M,512]) @ pw[512,512]^T =================
// ROUND-6 structure (best measured): 256x256 tile, BK=64, 8 waves, dbuf LDS,
// reg-staged; per iter: writeAB(kt+1) -> load(kt+2) -> 64 MFMA -> lgkm+bar.
// fp32 A converted in-register via v_cvt_pk_bf16_f32.
__global__ __launch_bounds__(512, 2) void k_gemm1(const float* __restrict__ A,
                                                  const ushort* __restrict__ Bm,
                                                  ushort* __restrict__ Cout) {
  __shared__ ushort sA[2][256 * 64];
  __shared__ ushort sB[2][256 * 64];
  const int t = threadIdx.x;                 // 0..511
  const int w = t >> 6, l = t & 63;
  const int lg = l >> 4, li = l & 15;
  const int bid = blockIdx.x;                // 256 blocks
  const int f = (bid & 7) * 32 + (bid >> 3); // XCD-chunked: A-panel pairs co-XCD
  const int m0 = (f >> 1) * 256, n0 = (f & 1) * 256;
  const int wr = (w >> 2) * 128, wc = (w & 3) * 64;

  float4 fa[8];     // raw fp32 A for next tile
  short8v fb[4];    // bf16 B for next tile

  auto loadA = [&](int kt) {
#pragma unroll
    for (int i = 0; i < 4; ++i) {
      int s = i * 512 + t, row = s >> 3, pch = s & 7;
      const float* g = A + (size_t)(m0 + row) * CDIM + kt * 64 + pch * 8;
      fa[2 * i] = *(const float4*)g;
      fa[2 * i + 1] = *(const float4*)(g + 4);
    }
  };
  auto loadB = [&](int kt) {
#pragma unroll
    for (int i = 0; i < 4; ++i) {
      int s = i * 512 + t, row = s >> 3, pch = s & 7;
      fb[i] = *(const short8v*)(Bm + (size_t)(n0 + row) * CDIM + kt * 64 + pch * 8);
    }
  };
  auto writeAB = [&](int buf) {
#pragma unroll
    for (int i = 0; i < 4; ++i) {
      int s = i * 512 + t, row = s >> 3, pch = s & 7;
      int off = row * 128 + ((pch ^ (row & 7)) << 4);
      uintx4 pk;
      pk.x = cvtpk(fa[2 * i].x, fa[2 * i].y);
      pk.y = cvtpk(fa[2 * i].z, fa[2 * i].w);
      pk.z = cvtpk(fa[2 * i + 1].x, fa[2 * i + 1].y);
      pk.w = cvtpk(fa[2 * i + 1].z, fa[2 * i + 1].w);
      *(uintx4*)((char*)sA[buf] + off) = pk;
      *(short8v*)((char*)sB[buf] + off) = fb[i];
    }
  };

  floatx4 acc[8][4] = {};

  // prologue: stage tile 0, prefetch tile 1 into regs
  loadA(0); loadB(0);
  writeAB(0);
  loadA(1); loadB(1);
  WAIT_LGKM0;
  sbar();

#pragma unroll
  for (int kt = 0; kt < 8; ++kt) {
    const int cur = kt & 1;
    if (kt < 7) writeAB(cur ^ 1);            // ds_write tile kt+1 (regs from prev iter)
    if (kt < 6) { loadA(kt + 2); loadB(kt + 2); }  // in flight across barrier
    // compute tile kt
#pragma unroll
    for (int kk = 0; kk < 2; ++kk) {
      int colb = (kk * 32 + lg * 8) * 2;
      short8v bf[4];
#pragma unroll
      for (int n = 0; n < 4; ++n)
        bf[n] = *(const short8v*)((const char*)sB[cur] + swz(wc + n * 16 + li, colb));
#pragma unroll
      for (int mh = 0; mh < 2; ++mh) {
        short8v af[4];
#pragma unroll
        for (int m = 0; m < 4; ++m)
          af[m] = *(const short8v*)((const char*)sA[cur] + swz(wr + mh * 64 + m * 16 + li, colb));
#pragma unroll
        for (int m = 0; m < 4; ++m)
#pragma unroll
          for (int n = 0; n < 4; ++n)
            acc[mh * 4 + m][n] = mfma16(af[m], bf[n], acc[mh * 4 + m][n]);
      }
    }
    if (kt < 7) { WAIT_LGKM0; sbar(); }
  }

#pragma unroll
  for (int m = 0; m < 8; ++m)
#pragma unroll
    for (int n = 0; n < 4; ++n) {
      int col = n0 + wc + n * 16 + li;
#pragma unroll
      for (int r = 0; r < 4; ++r) {
        int row = m0 + wr + m * 16 + lg * 4 + r;
        Cout[(size_t)row * CDIM + col] = f2bf(acc[m][n][r]);
      }
    }
}

// ================= gemm3: out[b,n,d] = sum_hq attnT[b,h,n,q]*M2T[b,d,hq] + bias =================
// ROUND-6 structure; bf16 A,B reg-staged; b == XCD (L2-local slab).
__global__ __launch_bounds__(512, 2) void k_gemm3(const ushort* __restrict__ attnT, // [b,8,4096,64]
                                                  const ushort* __restrict__ M2T,   // [b,512,512]
                                                  float* __restrict__ out,          // [b,4096,512]
                                                  const float* __restrict__ bias) {
  __shared__ ushort sA[2][256 * 64];
  __shared__ ushort sB[2][256 * 64];
  const int t = threadIdx.x;
  const int w = t >> 6, l = t & 63;
  const int lg = l >> 4, li = l & 15;
  const int bid = blockIdx.x;          // 256
  const int b = bid & 7;               // one batch per XCD
  const int idx = bid >> 3;            // 0..31
  const int m0 = (idx >> 1) * 256, n0 = (idx & 1) * 256;
  const int wr = (w >> 2) * 128, wc = (w & 3) * 64;
  const ushort* Bb = M2T + (size_t)b * 262144;

  short8v fA[4], fB[4];
  auto loadAB = [&](int kt) {
#pragma unroll
    for (int i = 0; i < 4; ++i) {
      int s = i * 512 + t, row = s >> 3, pch = s & 7;
      fA[i] = *(const short8v*)(attnT + (((size_t)(b * 8 + kt)) * NTOK + m0 + row) * 64 + pch * 8);
      fB[i] = *(const short8v*)(Bb + (size_t)(n0 + row) * CDIM + kt * 64 + pch * 8);
    }
  };
  auto writeAB = [&](int buf) {
#pragma unroll
    for (int i = 0; i < 4; ++i) {
      int s = i * 512 + t, row = s >> 3, pch = s & 7;
      int off = row * 128 + ((pch ^ (row & 7)) << 4);
      *(short8v*)((char*)sA[buf] + off) = fA[i];
      *(short8v*)((char*)sB[buf] + off) = fB[i];
    }
  };

  floatx4 acc[8][4] = {};

  loadAB(0);
  writeAB(0);
  loadAB(1);
  WAIT_LGKM0;
  sbar();

#pragma unroll
  for (int kt = 0; kt < 8; ++kt) {
    const int cur = kt & 1;
    if (kt < 7) writeAB(cur ^ 1);
    if (kt < 6) loadAB(kt + 2);
#pragma unroll
    for (int kk = 0; kk < 2; ++kk) {
      int colb = (kk * 32 + lg * 8) * 2;
      short8v bf[4];
#pragma unroll
      for (int n = 0; n < 4; ++n)
        bf[n] = *(const short8v*)((const char*)sB[cur] + swz(wc + n * 16 + li, colb));
#pragma unroll
      for (int mh = 0; mh < 2; ++mh) {
        short8v af[4];
#pragma unroll
        for (int m = 0; m < 4; ++m)
          af[m] = *(const short8v*)((const char*)sA[cur] + swz(wr + mh * 64 + m * 16 + li, colb));
#pragma unroll
        for (int m = 0; m < 4; ++m)
#pragma unroll
          for (int n = 0; n < 4; ++n)
            acc[mh * 4 + m][n] = mfma16(af[m], bf[n], acc[mh * 4 + m][n]);
      }
    }
    if (kt < 7) { WAIT_LGKM0; sbar(); }
  }

#pragma unroll
  for (int m = 0; m < 8; ++m)
#pragma unroll
    for (int n = 0; n < 4; ++n) {
      int col = n0 + wc + n * 16 + li;
      float bv = bias[col];
#pragma unroll
      for (int r = 0; r < 4; ++r) {
        int row = m0 + wr + m * 16 + lg * 4 + r;
        out[((size_t)b * NTOK + row) * CDIM + col] = acc[m][n][r] + bv;
      }
    }
}

// ---------------- adaptive 8x8 pool + pre-swizzled bf16 Q tiles ----------------
__global__ __launch_bounds__(256) void k_pool(const ushort* __restrict__ wm,
                                              float* __restrict__ rep,
                                              ushort* __restrict__ qbf) {
  const int blk = blockIdx.x;      // b*64 + qi
  const int b = blk >> 6, qi = blk & 63;
  const int ph = qi >> 3, pw = qi & 7;
  const int c0 = threadIdx.x * 2;
  float a0 = 0.f, a1 = 0.f;
  for (int u = 0; u < 64; ++u) {
    int n = (ph * 8 + (u >> 3)) * 64 + pw * 8 + (u & 7);
    unsigned v = *(const unsigned*)(wm + ((size_t)b * NTOK + n) * CDIM + c0);
    a0 += bf2f((ushort)(v & 0xffff));
    a1 += bf2f((ushort)(v >> 16));
  }
  a0 *= 0.015625f; a1 *= 0.015625f;
  float* dst = rep + ((size_t)b * 64 + qi) * CDIM + c0;
  dst[0] = a0;
  dst[1] = a1;
  // bf16 Q tile, swizzled layout per (b,h): [64 q][64 d]
  int h = c0 >> 6, d0 = c0 & 63;   // d0 even
  unsigned pack = (unsigned)f2bf(a0) | ((unsigned)f2bf(a1) << 16);
  *(unsigned*)((char*)qbf + ((size_t)(b * 8 + h)) * 8192 + swz(qi, d0 * 2)) = pack;
}

// ---------------- qkexp: per (bh, chunk of 256 keys; 2 sub-tiles of 128) ----------------
__global__ __launch_bounds__(256) void k_qkexp(const ushort* __restrict__ wmat,
                                               const ushort* __restrict__ qbf,
                                               ushort* __restrict__ attnT,  // [bh,4096,64]
                                               float* __restrict__ pvP,     // [bh,16,64,64]
                                               float* __restrict__ rsumP) { // [bh,16,64]
  __shared__ char smem[57344] __attribute__((aligned(128)));
  ushort* sQ  = (ushort*)smem;            // [64 q][64 d]   8KB swizzled
  ushort* sK  = (ushort*)(smem + 8192);   // [128 n][64 d] 16KB swizzled
  ushort* sVT = (ushort*)(smem + 24576);  // [64 d][128 n] 16KB swizzled (256B rows)
  ushort* sP  = (ushort*)(smem + 40960);  // [64 q][128 k] 16KB swizzled (256B rows)

  const int bh = blockIdx.y, ch = blockIdx.x;
  const int b = bh >> 3, h = bh & 7;
  const int t = threadIdx.x, w = t >> 6, l = t & 63;
  const int lg = l >> 4, li = l & 15;

  // stage Q (pre-swizzled in qbf -> linear copy)
  {
    const char* qsrc = (const char*)(qbf + (size_t)bh * 4096);
#pragma unroll
    for (int i = 0; i < 2; ++i) {
      int flat = i * 256 + t;
      GLD_LDS16(qsrc + flat * 16, (char*)sQ + flat * 16);
    }
  }

  float rs[4] = {};
  floatx4 pv[4] = {};
  short8v qa[2];
  bool qaLoaded = false;

  for (int sc = 0; sc < 2; ++sc) {
    const ushort* wbase = wmat + ((size_t)b * NTOK + ch * CHK + sc * 128) * CDIM + h * DH;
    __syncthreads();
    // stage K tile (source pre-swizzled)
#pragma unroll
    for (int i = 0; i < 4; ++i) {
      int flat = i * 256 + t;
      int row = flat >> 3, pch = flat & 7;
      int sch = pch ^ (row & 7);
      GLD_LDS16(wbase + (size_t)row * CDIM + sch * 8, (char*)sK + flat * 16);
    }
    // stage V transposed: [d][n] — packed u32 writes (n-pair per thread)
    {
      int u = t & 63;                 // n-pair: columns 2u, 2u+1
      int dh2 = (t >> 6) * 16;        // 16 d's
      const ushort* g0 = wbase + (size_t)(2 * u) * CDIM + dh2;
      const ushort* g1 = g0 + CDIM;
      short8v a0 = *(const short8v*)g0;
      short8v a1 = *(const short8v*)(g0 + 8);
      short8v b0 = *(const short8v*)g1;
      short8v b1 = *(const short8v*)(g1 + 8);
#pragma unroll
      for (int j = 0; j < 8; ++j) {
        unsigned w0 = ((unsigned)(ushort)a0[j]) | (((unsigned)(ushort)b0[j]) << 16);
        *(unsigned*)((char*)sVT + swz256(dh2 + j, 4 * u)) = w0;
        unsigned w1 = ((unsigned)(ushort)a1[j]) | (((unsigned)(ushort)b1[j]) << 16);
        *(unsigned*)((char*)sVT + swz256(dh2 + 8 + j, 4 * u)) = w1;
      }
    }
    __syncthreads();

    if (!qaLoaded) {
      qaLoaded = true;
#pragma unroll
      for (int kk = 0; kk < 2; ++kk)
        qa[kk] = *(const short8v*)((const char*)sQ + swz(w * 16 + li, (kk * 32 + lg * 8) * 2));
    }

    // QK^T
    floatx4 s[8] = {};
#pragma unroll
    for (int kk = 0; kk < 2; ++kk) {
      int cb = (kk * 32 + lg * 8) * 2;
#pragma unroll
      for (int kf = 0; kf < 8; ++kf) {
        short8v kb = *(const short8v*)((const char*)sK + swz(kf * 16 + li, cb));
        s[kf] = mfma16(qa[kk], kb, s[kf]);
      }
    }

    // exp, rowsum partial, attnT store, sP write
#pragma unroll
    for (int kf = 0; kf < 8; ++kf) {
      ushort pb[4];
#pragma unroll
      for (int r = 0; r < 4; ++r) {
        float p = __expf(s[kf][r] * SCALE);
        rs[r] += p;
        pb[r] = f2bf(p);
        int q = w * 16 + lg * 4 + r;
        *(ushort*)((char*)sP + swz256(q, (kf * 16 + li) * 2)) = pb[r];
      }
      int key = ch * CHK + sc * 128 + kf * 16 + li;
      ushort4 pk; pk.x = pb[0]; pk.y = pb[1]; pk.z = pb[2]; pk.w = pb[3];
      *(ushort4*)(attnT + ((size_t)bh * NTOK + key) * 64 + w * 16 + lg * 4) = pk;
    }

    // PV partial accumulate over these 128 keys
#pragma unroll
    for (int kk4 = 0; kk4 < 4; ++kk4) {
      int cb = kk4 * 64 + lg * 16;
      short8v pa = *(const short8v*)((const char*)sP + swz256(w * 16 + li, cb));
#pragma unroll
      for (int nf = 0; nf < 4; ++nf) {
        short8v vb = *(const short8v*)((const char*)sVT + swz256(nf * 16 + li, cb));
        pv[nf] = mfma16(pa, vb, pv[nf]);
      }
    }
  }

#pragma unroll
  for (int r = 0; r < 4; ++r) {
    float v = rs[r];
    for (int mask = 1; mask < 16; mask <<= 1) v += __shfl_xor(v, mask);
    if (li == 0) rsumP[((size_t)bh * NCH + ch) * 64 + w * 16 + lg * 4 + r] = v;
  }
  float* pvdst = pvP + ((size_t)bh * NCH + ch) * 4096;
#pragma unroll
  for (int nf = 0; nf < 4; ++nf)
#pragma unroll
    for (int r = 0; r < 4; ++r)
      pvdst[(w * 16 + lg * 4 + r) * 64 + nf * 16 + li] = pv[nf][r];
}

// ---------------- midm2: chunk-reduce + reph update + self-attn + xd + M2T ----------------
// to_out_w read as fp32 and converted inline (saves the tow f2bf pass).
__global__ __launch_bounds__(256) void k_midm2(const float* __restrict__ rep,
                                               const float* __restrict__ pvP,
                                               const float* __restrict__ rsumP,
                                               const float* __restrict__ step_rep,
                                               const float* __restrict__ step_x,
                                               const float* __restrict__ tow,   // fp32 [512,512]
                                               ushort* __restrict__ m2t) {
  __shared__ float sSum[64];
  __shared__ float sRd[4096];
  __shared__ float sR[64 * 65];
  __shared__ float sT[64 * 65];
  __shared__ ushort sXd[4096];   // [64 q][64 dd] swizzled bf16
  const int bh = blockIdx.x;
  const int b = bh >> 3, h = bh & 7;
  const int t = threadIdx.x, w = t >> 6, l = t & 63;
  const int lg = l >> 4, li = l & 15;

  if (t < 64) {
    float v = 0.f;
#pragma unroll
    for (int ch = 0; ch < NCH; ++ch) v += rsumP[((size_t)bh * NCH + ch) * 64 + t];
    sSum[t] = v;
  }
  {
    const float* p = pvP + (size_t)bh * NCH * 4096;
#pragma unroll
    for (int j = 0; j < 16; ++j) {
      int idx = t + 256 * j;
      float sm = 0.f;
#pragma unroll
      for (int ch = 0; ch < NCH; ++ch) sm += p[ch * 4096 + idx];
      sRd[idx] = sm;
    }
  }
  __syncthreads();
  {
    int q = t >> 2, d0 = (t & 3) * 16;
    float srep = step_rep[h];
    float inv = 1.f / sSum[q];
    const float* rp = rep + ((size_t)b * 64 + q) * CDIM + h * DH + d0;
#pragma unroll
    for (int j = 0; j < 16; ++j) sR[q * 65 + d0 + j] = rp[j] + srep * (sRd[q * 64 + d0 + j] * inv);
  }
  __syncthreads();
  {
    int q = t >> 2, jb = (t & 3) * 16;
    float a[16];
#pragma unroll
    for (int j = 0; j < 16; ++j) {
      float accd = 0.f;
      for (int d = 0; d < 64; ++d) accd += sR[q * 65 + d] * sR[(jb + j) * 65 + d];
      a[j] = accd * SCALE;
    }
    float mx = a[0];
#pragma unroll
    for (int j = 1; j < 16; ++j) mx = fmaxf(mx, a[j]);
    mx = fmaxf(mx, __shfl_xor(mx, 1));
    mx = fmaxf(mx, __shfl_xor(mx, 2));
    float sm = 0.f;
#pragma unroll
    for (int j = 0; j < 16; ++j) { a[j] = __expf(a[j] - mx); sm += a[j]; }
    sm += __shfl_xor(sm, 1);
    sm += __shfl_xor(sm, 2);
    float inv = 1.f / sm;
#pragma unroll
    for (int j = 0; j < 16; ++j) sT[q * 65 + jb + j] = a[j] * inv;
  }
  __syncthreads();
  {
    int q = t >> 2, db = (t & 3) * 16;
    float accd[16] = {};
    for (int j = 0; j < 64; ++j) {
      float w2 = sT[q * 65 + j];
#pragma unroll
      for (int d = 0; d < 16; ++d) accd[d] += w2 * sR[j * 65 + db + d];
    }
    float sc = step_x[h] / sSum[q];
    ushort o[16] __attribute__((aligned(16)));
#pragma unroll
    for (int d = 0; d < 16; ++d) o[d] = f2bf(accd[d] * sc);
    *(short8v*)((char*)sXd + swz(q, db * 2)) = *(short8v*)&o[0];
    *(short8v*)((char*)sXd + swz(q, db * 2 + 16)) = *(short8v*)&o[8];
  }
  __syncthreads();
  // m2: wave w covers d rows [w*128,(w+1)*128); tow fp32 converted inline
  floatx4 acc[8][4] = {};
#pragma unroll
  for (int kk = 0; kk < 2; ++kk) {
    int dd0 = kk * 32 + lg * 8;
    short8v bf[4];
#pragma unroll
    for (int nf = 0; nf < 4; ++nf)
      bf[nf] = *(const short8v*)((const char*)sXd + swz(nf * 16 + li, dd0 * 2));
#pragma unroll
    for (int m = 0; m < 8; ++m) {
      int d = w * 128 + m * 16 + li;
      const float* g = tow + (size_t)d * CDIM + h * DH + dd0;
      float4 lo = *(const float4*)g;
      float4 hi = *(const float4*)(g + 4);
      uintx4 u;
      u.x = cvtpk(lo.x, lo.y); u.y = cvtpk(lo.z, lo.w);
      u.z = cvtpk(hi.x, hi.y); u.w = cvtpk(hi.z, hi.w);
      short8v af = *(short8v*)&u;
#pragma unroll
      for (int nf = 0; nf < 4; ++nf) acc[m][nf] = mfma16(af, bf[nf], acc[m][nf]);
    }
  }
#pragma unroll
  for (int m = 0; m < 8; ++m)
#pragma unroll
    for (int nf = 0; nf < 4; ++nf)
#pragma unroll
      for (int r = 0; r < 4; ++r) {
        int d = w * 128 + m * 16 + lg * 4 + r;
        int hq = h * 64 + nf * 16 + li;
        m2t[((size_t)b * CDIM + d) * CDIM + hq] = f2bf(acc[m][nf][r]);
      }
}

// ---------------- launch ----------------
extern "C" void kernel_launch(void* const* d_in, const int* in_sizes, int n_in,
                              void* d_out, int out_size, void* d_ws, size_t ws_size,
                              hipStream_t stream) {
  const float* x = (const float*)d_in[0];
  const float* proj_w = (const float*)d_in[1];
  const float* step_rep = (const float*)d_in[2];
  const float* step_x = (const float*)d_in[3];
  const float* to_out_w = (const float*)d_in[4];
  const float* to_out_b = (const float*)d_in[5];
  float* out = (float*)d_out;
  char* ws = (char*)d_ws;
  char* ob = (char*)d_out;   // d_out doubles as scratch until gemm3 overwrites it

  // ws layout:
  ushort* bufA = (ushort*)(ws);                  // attnT                  (32 MiB)
  ushort* bufB = (ushort*)(ws + 33554432);       // w bf16 -> M2T overlay  (32 MiB)
  ushort* pw   = (ushort*)(ws + 67108864);       // proj_w bf16 (512 KiB)
  float*  rep  = (float*)(ws + 68157440);        // pooled rep fp32 (1 MiB)
  // d_out scratch (all dead before gemm3 writes out):
  float*  pvP   = (float*)(ob);                  // PV partials (16.8 MiB)
  ushort* qbf   = (ushort*)(ob + 34603008);      // pre-swizzled Q tiles (512 KiB)
  float*  rsumP = (float*)(ob + 35127296);       // rowsum partials (256 KiB)
  ushort* m2t   = bufB;                          // M2T overlays w after qkexp

  k_f2bfw1<<<256, 256, 0, stream>>>(proj_w, pw);

  k_gemm1<<<256, 512, 0, stream>>>(x, pw, bufB);

  k_pool<<<Bc * 64, 256, 0, stream>>>(bufB, rep, qbf);

  k_qkexp<<<dim3(NCH, Bc * HEADS), 256, 0, stream>>>(bufB, qbf, bufA, pvP, rsumP);

  k_midm2<<<Bc * HEADS, 256, 0, stream>>>(rep, pvP, rsumP, step_rep, step_x, to_out_w, m2t);

  k_gemm3<<<256, 512, 0, stream>>>(bufA, m2t, out, to_out_b);
}

// Round 13
// 107.661 us; speedup vs baseline: 1.1580x; 1.0518x over previous
//
#include <hip/hip_runtime.h>
#include <hip/hip_bf16.h>
#include <stdint.h>

// ---------------- common types / helpers ----------------
typedef __attribute__((ext_vector_type(8))) short short8v;   // 8 x bf16 (4 VGPRs)
typedef __attribute__((ext_vector_type(4))) float floatx4;
typedef __attribute__((ext_vector_type(4))) unsigned uintx4;

#define DEV __device__ __forceinline__

DEV ushort f2bf(float f) {                      // RNE float -> bf16 bits
  union { float f; unsigned u; } v; v.f = f;
  unsigned r = v.u + 0x7fffu + ((v.u >> 16) & 1u);
  return (ushort)(r >> 16);
}
DEV float bf2f(ushort b) {
  union { unsigned u; float f; } v; v.u = ((unsigned)b) << 16;
  return v.f;
}
DEV unsigned cvtpk(float lo, float hi) {        // packed f32->bf16 (RNE), 1 inst
  unsigned r;
  asm("v_cvt_pk_bf16_f32 %0, %1, %2" : "=v"(r) : "v"(lo), "v"(hi));
  return r;
}
// XOR swizzle for 64-col bf16 tiles (128B rows)
DEV int swz(int row, int colByte) {
  return row * 128 + (colByte ^ ((row & 7) << 4));
}
// XOR swizzle for 128-col bf16 tiles (256B rows)
DEV int swz256(int row, int colByte) {
  return row * 256 + (colByte ^ ((row & 7) << 4));
}
DEV floatx4 mfma16(short8v a, short8v b, floatx4 c) {
  return __builtin_amdgcn_mfma_f32_16x16x32_bf16(a, b, c, 0, 0, 0);
}

#define GLD_LDS16(g, l)                                                   \
  __builtin_amdgcn_global_load_lds(                                       \
      (const __attribute__((address_space(1))) void*)(g),                 \
      (__attribute__((address_space(3))) void*)(l), 16, 0, 0)

#define WAIT_LGKM0 asm volatile("s_waitcnt lgkmcnt(0)" ::: "memory")
DEV void sbar() {
  __builtin_amdgcn_sched_barrier(0);
  __builtin_amdgcn_s_barrier();
  __builtin_amdgcn_sched_barrier(0);
}

// problem constants
constexpr int Bc = 8, HEADS = 8, NTOK = 4096, CDIM = 512, DH = 64;
constexpr float SCALE = 0.125f;   // DH^-0.5
constexpr int NCH = 8, CHK = 512;    // key chunks for qkexp (4 sub-tiles of 128)

// ================= gemm1: w[M,512] = bf16(x[M,512]) @ bf16(proj_w)^T =================
// ROUND-6 structure (best measured): 256x256 tile, BK=64, 8 waves, dbuf LDS,
// reg-staged; per iter: writeAB(kt+1) -> load(kt+2) -> 64 MFMA -> lgkm+bar.
// BOTH A and B are fp32 in global, converted in-register via v_cvt_pk_bf16_f32
// (no separate weight-conversion pass).
__global__ __launch_bounds__(512, 2) void k_gemm1(const float* __restrict__ A,
                                                  const float* __restrict__ Bw,
                                                  ushort* __restrict__ Cout) {
  __shared__ ushort sA[2][256 * 64];
  __shared__ ushort sB[2][256 * 64];
  const int t = threadIdx.x;                 // 0..511
  const int w = t >> 6, l = t & 63;
  const int lg = l >> 4, li = l & 15;
  const int bid = blockIdx.x;                // 256 blocks
  const int f = (bid & 7) * 32 + (bid >> 3); // XCD-chunked: A-panel pairs co-XCD
  const int m0 = (f >> 1) * 256, n0 = (f & 1) * 256;
  const int wr = (w >> 2) * 128, wc = (w & 3) * 64;

  float4 fa[8];     // raw fp32 A for next tile
  float4 fb[8];     // raw fp32 B for next tile

  auto loadA = [&](int kt) {
#pragma unroll
    for (int i = 0; i < 4; ++i) {
      int s = i * 512 + t, row = s >> 3, pch = s & 7;
      const float* g = A + (size_t)(m0 + row) * CDIM + kt * 64 + pch * 8;
      fa[2 * i] = *(const float4*)g;
      fa[2 * i + 1] = *(const float4*)(g + 4);
    }
  };
  auto loadB = [&](int kt) {
#pragma unroll
    for (int i = 0; i < 4; ++i) {
      int s = i * 512 + t, row = s >> 3, pch = s & 7;
      const float* g = Bw + (size_t)(n0 + row) * CDIM + kt * 64 + pch * 8;
      fb[2 * i] = *(const float4*)g;
      fb[2 * i + 1] = *(const float4*)(g + 4);
    }
  };
  auto writeAB = [&](int buf) {
#pragma unroll
    for (int i = 0; i < 4; ++i) {
      int s = i * 512 + t, row = s >> 3, pch = s & 7;
      int off = row * 128 + ((pch ^ (row & 7)) << 4);
      uintx4 pk;
      pk.x = cvtpk(fa[2 * i].x, fa[2 * i].y);
      pk.y = cvtpk(fa[2 * i].z, fa[2 * i].w);
      pk.z = cvtpk(fa[2 * i + 1].x, fa[2 * i + 1].y);
      pk.w = cvtpk(fa[2 * i + 1].z, fa[2 * i + 1].w);
      *(uintx4*)((char*)sA[buf] + off) = pk;
      uintx4 qk;
      qk.x = cvtpk(fb[2 * i].x, fb[2 * i].y);
      qk.y = cvtpk(fb[2 * i].z, fb[2 * i].w);
      qk.z = cvtpk(fb[2 * i + 1].x, fb[2 * i + 1].y);
      qk.w = cvtpk(fb[2 * i + 1].z, fb[2 * i + 1].w);
      *(uintx4*)((char*)sB[buf] + off) = qk;
    }
  };

  floatx4 acc[8][4] = {};

  // prologue: stage tile 0, prefetch tile 1 into regs
  loadA(0); loadB(0);
  writeAB(0);
  loadA(1); loadB(1);
  WAIT_LGKM0;
  sbar();

#pragma unroll
  for (int kt = 0; kt < 8; ++kt) {
    const int cur = kt & 1;
    if (kt < 7) writeAB(cur ^ 1);            // ds_write tile kt+1 (regs from prev iter)
    if (kt < 6) { loadA(kt + 2); loadB(kt + 2); }  // in flight across barrier
    // compute tile kt
#pragma unroll
    for (int kk = 0; kk < 2; ++kk) {
      int colb = (kk * 32 + lg * 8) * 2;
      short8v bf[4];
#pragma unroll
      for (int n = 0; n < 4; ++n)
        bf[n] = *(const short8v*)((const char*)sB[cur] + swz(wc + n * 16 + li, colb));
#pragma unroll
      for (int mh = 0; mh < 2; ++mh) {
        short8v af[4];
#pragma unroll
        for (int m = 0; m < 4; ++m)
          af[m] = *(const short8v*)((const char*)sA[cur] + swz(wr + mh * 64 + m * 16 + li, colb));
#pragma unroll
        for (int m = 0; m < 4; ++m)
#pragma unroll
          for (int n = 0; n < 4; ++n)
            acc[mh * 4 + m][n] = mfma16(af[m], bf[n], acc[mh * 4 + m][n]);
      }
    }
    if (kt < 7) { WAIT_LGKM0; sbar(); }
  }

#pragma unroll
  for (int m = 0; m < 8; ++m)
#pragma unroll
    for (int n = 0; n < 4; ++n) {
      int col = n0 + wc + n * 16 + li;
#pragma unroll
      for (int r = 0; r < 4; ++r) {
        int row = m0 + wr + m * 16 + lg * 4 + r;
        Cout[(size_t)row * CDIM + col] = f2bf(acc[m][n][r]);
      }
    }
}

// ================= gemm3: out[b,n,d] = sum_hq attnT[b,h,n,q]*M2T[b,d,hq] + bias =================
// ROUND-6 structure; bf16 A,B reg-staged; b == XCD (L2-local slab).
__global__ __launch_bounds__(512, 2) void k_gemm3(const ushort* __restrict__ attnT, // [b,8,4096,64]
                                                  const ushort* __restrict__ M2T,   // [b,512,512]
                                                  float* __restrict__ out,          // [b,4096,512]
                                                  const float* __restrict__ bias) {
  __shared__ ushort sA[2][256 * 64];
  __shared__ ushort sB[2][256 * 64];
  const int t = threadIdx.x;
  const int w = t >> 6, l = t & 63;
  const int lg = l >> 4, li = l & 15;
  const int bid = blockIdx.x;          // 256
  const int b = bid & 7;               // one batch per XCD
  const int idx = bid >> 3;            // 0..31
  const int m0 = (idx >> 1) * 256, n0 = (idx & 1) * 256;
  const int wr = (w >> 2) * 128, wc = (w & 3) * 64;
  const ushort* Bb = M2T + (size_t)b * 262144;

  short8v fA[4], fB[4];
  auto loadAB = [&](int kt) {
#pragma unroll
    for (int i = 0; i < 4; ++i) {
      int s = i * 512 + t, row = s >> 3, pch = s & 7;
      fA[i] = *(const short8v*)(attnT + (((size_t)(b * 8 + kt)) * NTOK + m0 + row) * 64 + pch * 8);
      fB[i] = *(const short8v*)(Bb + (size_t)(n0 + row) * CDIM + kt * 64 + pch * 8);
    }
  };
  auto writeAB = [&](int buf) {
#pragma unroll
    for (int i = 0; i < 4; ++i) {
      int s = i * 512 + t, row = s >> 3, pch = s & 7;
      int off = row * 128 + ((pch ^ (row & 7)) << 4);
      *(short8v*)((char*)sA[buf] + off) = fA[i];
      *(short8v*)((char*)sB[buf] + off) = fB[i];
    }
  };

  floatx4 acc[8][4] = {};

  loadAB(0);
  writeAB(0);
  loadAB(1);
  WAIT_LGKM0;
  sbar();

#pragma unroll
  for (int kt = 0; kt < 8; ++kt) {
    const int cur = kt & 1;
    if (kt < 7) writeAB(cur ^ 1);
    if (kt < 6) loadAB(kt + 2);
#pragma unroll
    for (int kk = 0; kk < 2; ++kk) {
      int colb = (kk * 32 + lg * 8) * 2;
      short8v bf[4];
#pragma unroll
      for (int n = 0; n < 4; ++n)
        bf[n] = *(const short8v*)((const char*)sB[cur] + swz(wc + n * 16 + li, colb));
#pragma unroll
      for (int mh = 0; mh < 2; ++mh) {
        short8v af[4];
#pragma unroll
        for (int m = 0; m < 4; ++m)
          af[m] = *(const short8v*)((const char*)sA[cur] + swz(wr + mh * 64 + m * 16 + li, colb));
#pragma unroll
        for (int m = 0; m < 4; ++m)
#pragma unroll
          for (int n = 0; n < 4; ++n)
            acc[mh * 4 + m][n] = mfma16(af[m], bf[n], acc[mh * 4 + m][n]);
      }
    }
    if (kt < 7) { WAIT_LGKM0; sbar(); }
  }

#pragma unroll
  for (int m = 0; m < 8; ++m)
#pragma unroll
    for (int n = 0; n < 4; ++n) {
      int col = n0 + wc + n * 16 + li;
      float bv = bias[col];
#pragma unroll
      for (int r = 0; r < 4; ++r) {
        int row = m0 + wr + m * 16 + lg * 4 + r;
        out[((size_t)b * NTOK + row) * CDIM + col] = acc[m][n][r] + bv;
      }
    }
}

// ---------------- adaptive 8x8 pool + pre-swizzled bf16 Q tiles ----------------
__global__ __launch_bounds__(256) void k_pool(const ushort* __restrict__ wm,
                                              float* __restrict__ rep,
                                              ushort* __restrict__ qbf) {
  const int blk = blockIdx.x;      // b*64 + qi
  const int b = blk >> 6, qi = blk & 63;
  const int ph = qi >> 3, pw = qi & 7;
  const int c0 = threadIdx.x * 2;
  float a0 = 0.f, a1 = 0.f;
  for (int u = 0; u < 64; ++u) {
    int n = (ph * 8 + (u >> 3)) * 64 + pw * 8 + (u & 7);
    unsigned v = *(const unsigned*)(wm + ((size_t)b * NTOK + n) * CDIM + c0);
    a0 += bf2f((ushort)(v & 0xffff));
    a1 += bf2f((ushort)(v >> 16));
  }
  a0 *= 0.015625f; a1 *= 0.015625f;
  float* dst = rep + ((size_t)b * 64 + qi) * CDIM + c0;
  dst[0] = a0;
  dst[1] = a1;
  // bf16 Q tile, swizzled layout per (b,h): [64 q][64 d]
  int h = c0 >> 6, d0 = c0 & 63;   // d0 even
  unsigned pack = (unsigned)f2bf(a0) | ((unsigned)f2bf(a1) << 16);
  *(unsigned*)((char*)qbf + ((size_t)(b * 8 + h)) * 8192 + swz(qi, d0 * 2)) = pack;
}

// ---------------- qkexp: per (bh, chunk of 512 keys; 4 sub-tiles of 128) ----------------
__global__ __launch_bounds__(256) void k_qkexp(const ushort* __restrict__ wmat,
                                               const ushort* __restrict__ qbf,
                                               ushort* __restrict__ attnT,  // [bh,4096,64]
                                               float* __restrict__ pvP,     // [bh,8,64,64]
                                               float* __restrict__ rsumP) { // [bh,8,64]
  __shared__ char smem[57344] __attribute__((aligned(128)));
  ushort* sQ  = (ushort*)smem;            // [64 q][64 d]   8KB swizzled
  ushort* sK  = (ushort*)(smem + 8192);   // [128 n][64 d] 16KB swizzled
  ushort* sVT = (ushort*)(smem + 24576);  // [64 d][128 n] 16KB swizzled (256B rows)
  ushort* sP  = (ushort*)(smem + 40960);  // [64 q][128 k] 16KB swizzled (256B rows)

  const int bh = blockIdx.y, ch = blockIdx.x;
  const int b = bh >> 3, h = bh & 7;
  const int t = threadIdx.x, w = t >> 6, l = t & 63;
  const int lg = l >> 4, li = l & 15;

  // stage Q (pre-swizzled in qbf -> linear copy)
  {
    const char* qsrc = (const char*)(qbf + (size_t)bh * 4096);
#pragma unroll
    for (int i = 0; i < 2; ++i) {
      int flat = i * 256 + t;
      GLD_LDS16(qsrc + flat * 16, (char*)sQ + flat * 16);
    }
  }

  float rs[4] = {};
  floatx4 pv[4] = {};
  short8v qa[2];
  bool qaLoaded = false;

  for (int sc = 0; sc < 4; ++sc) {
    const ushort* wbase = wmat + ((size_t)b * NTOK + ch * CHK + sc * 128) * CDIM + h * DH;
    __syncthreads();
    // stage K tile (source pre-swizzled)
#pragma unroll
    for (int i = 0; i < 4; ++i) {
      int flat = i * 256 + t;
      int row = flat >> 3, pch = flat & 7;
      int sch = pch ^ (row & 7);
      GLD_LDS16(wbase + (size_t)row * CDIM + sch * 8, (char*)sK + flat * 16);
    }
    // stage V transposed: [d][n] — packed u32 writes (n-pair per thread)
    {
      int u = t & 63;                 // n-pair: columns 2u, 2u+1
      int dh2 = (t >> 6) * 16;        // 16 d's
      const ushort* g0 = wbase + (size_t)(2 * u) * CDIM + dh2;
      const ushort* g1 = g0 + CDIM;
      short8v a0 = *(const short8v*)g0;
      short8v a1 = *(const short8v*)(g0 + 8);
      short8v b0 = *(const short8v*)g1;
      short8v b1 = *(const short8v*)(g1 + 8);
#pragma unroll
      for (int j = 0; j < 8; ++j) {
        unsigned w0 = ((unsigned)(ushort)a0[j]) | (((unsigned)(ushort)b0[j]) << 16);
        *(unsigned*)((char*)sVT + swz256(dh2 + j, 4 * u)) = w0;
        unsigned w1 = ((unsigned)(ushort)a1[j]) | (((unsigned)(ushort)b1[j]) << 16);
        *(unsigned*)((char*)sVT + swz256(dh2 + 8 + j, 4 * u)) = w1;
      }
    }
    __syncthreads();

    if (!qaLoaded) {
      qaLoaded = true;
#pragma unroll
      for (int kk = 0; kk < 2; ++kk)
        qa[kk] = *(const short8v*)((const char*)sQ + swz(w * 16 + li, (kk * 32 + lg * 8) * 2));
    }

    // QK^T
    floatx4 s[8] = {};
#pragma unroll
    for (int kk = 0; kk < 2; ++kk) {
      int cb = (kk * 32 + lg * 8) * 2;
#pragma unroll
      for (int kf = 0; kf < 8; ++kf) {
        short8v kb = *(const short8v*)((const char*)sK + swz(kf * 16 + li, cb));
        s[kf] = mfma16(qa[kk], kb, s[kf]);
      }
    }

    // exp, rowsum partial, attnT store, sP write
#pragma unroll
    for (int kf = 0; kf < 8; ++kf) {
      ushort pb[4];
#pragma unroll
      for (int r = 0; r < 4; ++r) {
        float p = __expf(s[kf][r] * SCALE);
        rs[r] += p;
        pb[r] = f2bf(p);
        int q = w * 16 + lg * 4 + r;
        *(ushort*)((char*)sP + swz256(q, (kf * 16 + li) * 2)) = pb[r];
      }
      int key = ch * CHK + sc * 128 + kf * 16 + li;
      ushort4 pk; pk.x = pb[0]; pk.y = pb[1]; pk.z = pb[2]; pk.w = pb[3];
      *(ushort4*)(attnT + ((size_t)bh * NTOK + key) * 64 + w * 16 + lg * 4) = pk;
    }

    // PV partial accumulate over these 128 keys
#pragma unroll
    for (int kk4 = 0; kk4 < 4; ++kk4) {
      int cb = kk4 * 64 + lg * 16;
      short8v pa = *(const short8v*)((const char*)sP + swz256(w * 16 + li, cb));
#pragma unroll
      for (int nf = 0; nf < 4; ++nf) {
        short8v vb = *(const short8v*)((const char*)sVT + swz256(nf * 16 + li, cb));
        pv[nf] = mfma16(pa, vb, pv[nf]);
      }
    }
  }

#pragma unroll
  for (int r = 0; r < 4; ++r) {
    float v = rs[r];
    for (int mask = 1; mask < 16; mask <<= 1) v += __shfl_xor(v, mask);
    if (li == 0) rsumP[((size_t)bh * NCH + ch) * 64 + w * 16 + lg * 4 + r] = v;
  }
  float* pvdst = pvP + ((size_t)bh * NCH + ch) * 4096;
#pragma unroll
  for (int nf = 0; nf < 4; ++nf)
#pragma unroll
    for (int r = 0; r < 4; ++r)
      pvdst[(w * 16 + lg * 4 + r) * 64 + nf * 16 + li] = pv[nf][r];
}

// ---------------- midm2: chunk-reduce + reph update + self-attn + xd + M2T ----------------
// to_out_w read as fp32 and converted inline (no weight pre-pass anywhere).
__global__ __launch_bounds__(256) void k_midm2(const float* __restrict__ rep,
                                               const float* __restrict__ pvP,
                                               const float* __restrict__ rsumP,
                                               const float* __restrict__ step_rep,
                                               const float* __restrict__ step_x,
                                               const float* __restrict__ tow,   // fp32 [512,512]
                                               ushort* __restrict__ m2t) {
  __shared__ float sSum[64];
  __shared__ float sRd[4096];
  __shared__ float sR[64 * 65];
  __shared__ float sT[64 * 65];
  __shared__ ushort sXd[4096];   // [64 q][64 dd] swizzled bf16
  const int bh = blockIdx.x;
  const int b = bh >> 3, h = bh & 7;
  const int t = threadIdx.x, w = t >> 6, l = t & 63;
  const int lg = l >> 4, li = l & 15;

  if (t < 64) {
    float v = 0.f;
#pragma unroll
    for (int ch = 0; ch < NCH; ++ch) v += rsumP[((size_t)bh * NCH + ch) * 64 + t];
    sSum[t] = v;
  }
  {
    const float* p = pvP + (size_t)bh * NCH * 4096;
#pragma unroll
    for (int j = 0; j < 16; ++j) {
      int idx = t + 256 * j;
      float sm = 0.f;
#pragma unroll
      for (int ch = 0; ch < NCH; ++ch) sm += p[ch * 4096 + idx];
      sRd[idx] = sm;
    }
  }
  __syncthreads();
  {
    int q = t >> 2, d0 = (t & 3) * 16;
    float srep = step_rep[h];
    float inv = 1.f / sSum[q];
    const float* rp = rep + ((size_t)b * 64 + q) * CDIM + h * DH + d0;
#pragma unroll
    for (int j = 0; j < 16; ++j) sR[q * 65 + d0 + j] = rp[j] + srep * (sRd[q * 64 + d0 + j] * inv);
  }
  __syncthreads();
  {
    int q = t >> 2, jb = (t & 3) * 16;
    float a[16];
#pragma unroll
    for (int j = 0; j < 16; ++j) {
      float accd = 0.f;
      for (int d = 0; d < 64; ++d) accd += sR[q * 65 + d] * sR[(jb + j) * 65 + d];
      a[j] = accd * SCALE;
    }
    float mx = a[0];
#pragma unroll
    for (int j = 1; j < 16; ++j) mx = fmaxf(mx, a[j]);
    mx = fmaxf(mx, __shfl_xor(mx, 1));
    mx = fmaxf(mx, __shfl_xor(mx, 2));
    float sm = 0.f;
#pragma unroll
    for (int j = 0; j < 16; ++j) { a[j] = __expf(a[j] - mx); sm += a[j]; }
    sm += __shfl_xor(sm, 1);
    sm += __shfl_xor(sm, 2);
    float inv = 1.f / sm;
#pragma unroll
    for (int j = 0; j < 16; ++j) sT[q * 65 + jb + j] = a[j] * inv;
  }
  __syncthreads();
  {
    int q = t >> 2, db = (t & 3) * 16;
    float accd[16] = {};
    for (int j = 0; j < 64; ++j) {
      float w2 = sT[q * 65 + j];
#pragma unroll
      for (int d = 0; d < 16; ++d) accd[d] += w2 * sR[j * 65 + db + d];
    }
    float sc = step_x[h] / sSum[q];
    ushort o[16] __attribute__((aligned(16)));
#pragma unroll
    for (int d = 0; d < 16; ++d) o[d] = f2bf(accd[d] * sc);
    *(short8v*)((char*)sXd + swz(q, db * 2)) = *(short8v*)&o[0];
    *(short8v*)((char*)sXd + swz(q, db * 2 + 16)) = *(short8v*)&o[8];
  }
  __syncthreads();
  // m2: wave w covers d rows [w*128,(w+1)*128); tow fp32 converted inline
  floatx4 acc[8][4] = {};
#pragma unroll
  for (int kk = 0; kk < 2; ++kk) {
    int dd0 = kk * 32 + lg * 8;
    short8v bf[4];
#pragma unroll
    for (int nf = 0; nf < 4; ++nf)
      bf[nf] = *(const short8v*)((const char*)sXd + swz(nf * 16 + li, dd0 * 2));
#pragma unroll
    for (int m = 0; m < 8; ++m) {
      int d = w * 128 + m * 16 + li;
      const float* g = tow + (size_t)d * CDIM + h * DH + dd0;
      float4 lo = *(const float4*)g;
      float4 hi = *(const float4*)(g + 4);
      uintx4 u;
      u.x = cvtpk(lo.x, lo.y); u.y = cvtpk(lo.z, lo.w);
      u.z = cvtpk(hi.x, hi.y); u.w = cvtpk(hi.z, hi.w);
      short8v af = *(short8v*)&u;
#pragma unroll
      for (int nf = 0; nf < 4; ++nf) acc[m][nf] = mfma16(af, bf[nf], acc[m][nf]);
    }
  }
#pragma unroll
  for (int m = 0; m < 8; ++m)
#pragma unroll
    for (int nf = 0; nf < 4; ++nf)
#pragma unroll
      for (int r = 0; r < 4; ++r) {
        int d = w * 128 + m * 16 + lg * 4 + r;
        int hq = h * 64 + nf * 16 + li;
        m2t[((size_t)b * CDIM + d) * CDIM + hq] = f2bf(acc[m][nf][r]);
      }
}

// ---------------- launch ----------------
extern "C" void kernel_launch(void* const* d_in, const int* in_sizes, int n_in,
                              void* d_out, int out_size, void* d_ws, size_t ws_size,
                              hipStream_t stream) {
  const float* x = (const float*)d_in[0];
  const float* proj_w = (const float*)d_in[1];
  const float* step_rep = (const float*)d_in[2];
  const float* step_x = (const float*)d_in[3];
  const float* to_out_w = (const float*)d_in[4];
  const float* to_out_b = (const float*)d_in[5];
  float* out = (float*)d_out;
  char* ws = (char*)d_ws;
  char* ob = (char*)d_out;   // d_out doubles as scratch until gemm3 overwrites it

  // ws layout:
  ushort* bufA = (ushort*)(ws);                  // attnT                  (32 MiB)
  ushort* bufB = (ushort*)(ws + 33554432);       // w bf16 -> M2T overlay  (32 MiB)
  float*  rep  = (float*)(ws + 68157440);        // pooled rep fp32 (1 MiB)
  // d_out scratch (all dead before gemm3 writes out):
  float*  pvP   = (float*)(ob);                  // PV partials (8.4 MiB)
  ushort* qbf   = (ushort*)(ob + 34603008);      // pre-swizzled Q tiles (512 KiB)
  float*  rsumP = (float*)(ob + 35127296);       // rowsum partials (128 KiB)
  ushort* m2t   = bufB;                          // M2T overlays w after qkexp

  k_gemm1<<<256, 512, 0, stream>>>(x, proj_w, bufB);

  k_pool<<<Bc * 64, 256, 0, stream>>>(bufB, rep, qbf);

  k_qkexp<<<dim3(NCH, Bc * HEADS), 256, 0, stream>>>(bufB, qbf, bufA, pvP, rsumP);

  k_midm2<<<Bc * HEADS, 256, 0, stream>>>(rep, pvP, rsumP, step_rep, step_x, to_out_w, m2t);

  k_gemm3<<<256, 512, 0, stream>>>(bufA, m2t, out, to_out_b);
}